// Round 1
// baseline (103.279 us; speedup 1.0000x reference)
//
#include <hip/hip_runtime.h>
#include <stdint.h>

#define K_DIM 4096
#define N_DIM 11008
#define M_DIM 256
#define BK 64
#define BN 64
#define NT (K_DIM / BK)   // 64 K-tiles

typedef uint32_t u32;
using frag_ab = __attribute__((ext_vector_type(8))) short;   // 8 bf16 (4 VGPR)
using frag_cd = __attribute__((ext_vector_type(4))) float;   // 4 f32 acc

__device__ __forceinline__ u32 f2bf_rn(float f) {
    u32 u = __builtin_bit_cast(u32, f);
    return (u + 0x7FFFu + ((u >> 16) & 1u)) >> 16;   // round-to-nearest-even
}
__device__ __forceinline__ float bf2f(u32 b) {
    return __builtin_bit_cast(float, b << 16);
}

// Kernel 1: x f32 -> bf16 (RN) + per-row sums of the ROUNDED values (so the
// +32 trick's correction term cancels exactly).
__global__ __launch_bounds__(256) void prep_kernel(const float* __restrict__ x,
                                                   ushort* __restrict__ xbf,
                                                   float* __restrict__ rowsum) {
    const int row = blockIdx.x;
    const int tid = threadIdx.x;
    const float* xr = x + (size_t)row * K_DIM;
    ushort* br = xbf + (size_t)row * K_DIM;
    float s = 0.0f;
#pragma unroll
    for (int p = 0; p < 4; ++p) {
        int i = p * 1024 + tid * 4;
        float4 v = *reinterpret_cast<const float4*>(xr + i);
        u32 b0 = f2bf_rn(v.x), b1 = f2bf_rn(v.y), b2 = f2bf_rn(v.z), b3 = f2bf_rn(v.w);
        uint2 o;
        o.x = b0 | (b1 << 16);
        o.y = b2 | (b3 << 16);
        *reinterpret_cast<uint2*>(br + i) = o;
        s += bf2f(b0) + bf2f(b1) + bf2f(b2) + bf2f(b3);
    }
#pragma unroll
    for (int off = 32; off > 0; off >>= 1) s += __shfl_down(s, off, 64);
    __shared__ float wsum[4];
    if ((tid & 63) == 0) wsum[tid >> 6] = s;
    __syncthreads();
    if (tid == 0) rowsum[row] = wsum[0] + wsum[1] + wsum[2] + wsum[3];
}

// Kernel 2: out[256,11008] = xbf @ dequant(qw).  BM=256 (full M, qweight read
// exactly once from HBM), BN=64, BK=64.  4 waves, each owns a 64x64 output
// tile (4x4 fragments of 16x16x32 bf16 MFMA).  A-fragments load directly from
// L2-resident xbf; B unpacks int4 -> bf16(32+v) into XOR-swizzled LDS [n][k].
__global__ __launch_bounds__(256) void gemm_kernel(const int* __restrict__ qw,
                                                   const float* __restrict__ scales,
                                                   const float* __restrict__ zeroes,
                                                   const ushort* __restrict__ xbf,
                                                   const float* __restrict__ rowsum,
                                                   float* __restrict__ out) {
    __shared__ uint4 Bt[2][512];   // 2 x 8KB, swizzled [n][k] bf16

    const int tid  = threadIdx.x;
    const int lane = tid & 63;
    const int n0   = blockIdx.x * BN;
    const int m_base = (tid >> 6) * 64;

    // ---- B staging mapping: thread (g = tid>>6, nl = tid&63) loads, per
    // half s, 4 packed rows (k2 = t*32 + s*16 + g*4 + 0..3) at column n0+nl.
    // Each int32 holds one byte = 2 k-consecutive nibbles, so 4 rows unpack
    // to 8 consecutive k at fixed n -> one ds_write_b128 into Bt[n][k].
    const int nl = tid & 63;
    const int g  = tid >> 6;
    const int* qbase = qw + (size_t)(g * 4) * N_DIM + n0 + nl;
    int wr_off[2];
#pragma unroll
    for (int s = 0; s < 2; ++s)
        wr_off[s] = nl * 128 + (((4 * s + g) ^ (nl & 7)) << 4);   // XOR swizzle

    // ---- A fragment base: lane holds A[m = l&15][k-chunk (l>>4)*8 .. +7]
    const ushort* abase = xbf + (size_t)(m_base + (lane & 15)) * K_DIM + ((lane >> 4) * 8);

    // ---- B fragment read offsets (same swizzle)
    int rd_off[4][2];
#pragma unroll
    for (int nf = 0; nf < 4; ++nf)
#pragma unroll
        for (int ks = 0; ks < 2; ++ks) {
            int n_local = nf * 16 + (lane & 15);
            rd_off[nf][ks] = n_local * 128 + ((((ks * 4) + (lane >> 4)) ^ (n_local & 7)) << 4);
        }

    frag_cd acc[4][4];
#pragma unroll
    for (int a = 0; a < 4; ++a)
#pragma unroll
        for (int b = 0; b < 4; ++b)
            acc[a][b] = (frag_cd){0.f, 0.f, 0.f, 0.f};

    u32 q[2][4];
    frag_ab afA[4][2], afB[4][2];

    auto loadB = [&](int t) {
#pragma unroll
        for (int s = 0; s < 2; ++s)
#pragma unroll
            for (int r = 0; r < 4; ++r)
                q[s][r] = (u32)qbase[(size_t)(t * 32 + s * 16 + r) * N_DIM];
    };
    auto loadA = [&](frag_ab (&af)[4][2], int t) {
#pragma unroll
        for (int mf = 0; mf < 4; ++mf)
#pragma unroll
            for (int ks = 0; ks < 2; ++ks)
                af[mf][ks] = *reinterpret_cast<const frag_ab*>(
                    abase + (size_t)mf * 16 * K_DIM + t * 64 + ks * 32);
    };
    auto writeB = [&](int buf) {
#pragma unroll
        for (int s = 0; s < 2; ++s) {
            uint4 w;
            // bf16(32 + nibble) = 0x4200 | (nibble << 2); lo nibble = even k,
            // hi nibble = odd k -> packed pair per dword.
            w.x = 0x42004200u | ((q[s][0] & 15u) << 2) | ((q[s][0] & 0xF0u) << 14);
            w.y = 0x42004200u | ((q[s][1] & 15u) << 2) | ((q[s][1] & 0xF0u) << 14);
            w.z = 0x42004200u | ((q[s][2] & 15u) << 2) | ((q[s][2] & 0xF0u) << 14);
            w.w = 0x42004200u | ((q[s][3] & 15u) << 2) | ((q[s][3] & 0xF0u) << 14);
            *reinterpret_cast<uint4*>(reinterpret_cast<char*>(&Bt[buf][0]) + wr_off[s]) = w;
        }
    };
    auto compute = [&](frag_ab (&af)[4][2], int buf) {
#pragma unroll
        for (int ks = 0; ks < 2; ++ks)
#pragma unroll
            for (int nf = 0; nf < 4; ++nf) {
                frag_ab b = *reinterpret_cast<const frag_ab*>(
                    reinterpret_cast<const char*>(&Bt[buf][0]) + rd_off[nf][ks]);
#pragma unroll
                for (int mf = 0; mf < 4; ++mf)
                    acc[mf][nf] = __builtin_amdgcn_mfma_f32_16x16x32_bf16(
                        af[mf][ks], b, acc[mf][nf], 0, 0, 0);
            }
    };

    // prologue: stage tile 0
    loadB(0);
    loadA(afA, 0);
    writeB(0);
    __syncthreads();

    // 2-phase pipeline: issue t+1 loads, compute t, unpack-write t+1, barrier.
    for (int t = 0; t < NT; t += 2) {
        if (t + 1 < NT) { loadB(t + 1); loadA(afB, t + 1); }
        compute(afA, 0);
        if (t + 1 < NT) writeB(1);
        __syncthreads();
        if (t + 1 < NT) {
            if (t + 2 < NT) { loadB(t + 2); loadA(afA, t + 2); }
            compute(afB, 1);
            if (t + 2 < NT) writeB(0);
            __syncthreads();
        }
    }

    // epilogue: out = sc*acc - (32*sc + zero)*rowsum
    const int ncol = lane & 15;
    const int rgrp = lane >> 4;
    float sc[4], zp[4];
#pragma unroll
    for (int nf = 0; nf < 4; ++nf) {
        int n = n0 + nf * 16 + ncol;
        sc[nf] = scales[n];
        zp[nf] = zeroes[n] + 32.0f * sc[nf];
    }
    float rs[4][4];
#pragma unroll
    for (int mf = 0; mf < 4; ++mf)
#pragma unroll
        for (int j = 0; j < 4; ++j)
            rs[mf][j] = rowsum[m_base + mf * 16 + rgrp * 4 + j];
#pragma unroll
    for (int mf = 0; mf < 4; ++mf)
#pragma unroll
        for (int nf = 0; nf < 4; ++nf)
#pragma unroll
            for (int j = 0; j < 4; ++j) {
                int m = m_base + mf * 16 + rgrp * 4 + j;
                int n = n0 + nf * 16 + ncol;
                out[(size_t)m * N_DIM + n] = sc[nf] * acc[mf][nf][j] - zp[nf] * rs[mf][j];
            }
}

extern "C" void kernel_launch(void* const* d_in, const int* in_sizes, int n_in,
                              void* d_out, int out_size, void* d_ws, size_t ws_size,
                              hipStream_t stream) {
    const float* x      = (const float*)d_in[0];
    const int*   qw     = (const int*)d_in[1];
    const float* scales = (const float*)d_in[2];
    const float* zeroes = (const float*)d_in[3];
    float* out = (float*)d_out;

    ushort* xbf    = (ushort*)d_ws;                                   // 2 MB
    float*  rowsum = (float*)((char*)d_ws + (size_t)M_DIM * K_DIM * 2); // 1 KB

    prep_kernel<<<M_DIM, 256, 0, stream>>>(x, xbf, rowsum);
    gemm_kernel<<<N_DIM / BN, 256, 0, stream>>>(qw, scales, zeroes, xbf, rowsum, out);
}